// Round 1
// baseline (2466.098 us; speedup 1.0000x reference)
//
#include <hip/hip_runtime.h>
#include <math.h>

#define HD 512
#define VD 50257
#define TD 128
#define NB6 786   // ceil(50257/64)

// ---- ws layout (float offsets) ----
#define OFF_EMB     0u        // [128][1024]
#define OFF_X0      131072u   // [256][1536]  gi for layer0 (incl. b_ih0)
#define OFF_OUTS0   524288u   // [256][512]   layer0 outputs per cell
#define OFF_O       655360u   // [128][512]   projection inputs
#define OFF_BASE    720896u   // [2][1536]
#define OFF_IDX     723968u   // [128] int
#define OFF_H0      724096u   // [2][512] double-buffered
#define OFF_H1      725120u   // [2][512]
#define OFF_FLAGS   726144u   // [96*32] uint (128B-spaced slots)
#define OFF_PM      729216u   // [128] ull
#define OFF_PMPART  729472u   // [128*786] ull
#define OFF_SUMS    930688u   // [128*25]

__global__ void k_zero(float* p, int n){
  int i = blockIdx.x*256 + threadIdx.x;
  if (i < n) p[i] = 0.f;
}

__global__ void k_idx(const float* __restrict__ tgt, const float* __restrict__ sos,
                      int* __restrict__ idx){
  int t = blockIdx.x;
  const float* src = (t == 0) ? sos : (tgt + (size_t)(t-1)*VD);
  for (int v = threadIdx.x; v < VD; v += 256)
    if (src[v] > 0.5f) idx[t] = v;   // one-hot: exactly one writer
}

__global__ void k_emb(const float* __restrict__ embW, const float* __restrict__ embB,
                      const int* __restrict__ idx, float* __restrict__ emb){
  int t = blockIdx.x;
  int j = blockIdx.y*256 + threadIdx.x;    // 0..1023
  float v = embW[(size_t)j*VD + idx[t]] + embB[j];
  emb[t*1024 + j] = v > 0.f ? v : 0.f;
}

// base[tt][r] = b_ih0[r] + sum_c W_ih0[r][c] * iv[tt][c]   (c < 512)
__global__ void k_base(const float* __restrict__ Wih0, const float* __restrict__ bih0,
                       const float* __restrict__ iv, float* __restrict__ base){
  int wave = threadIdx.x >> 6, lane = threadIdx.x & 63;
  int o = blockIdx.x*4 + wave;            // 0..3071
  int tt = o / 1536, r = o % 1536;
  float s = 0.f;
  for (int c = lane; c < HD; c += 64)
    s += Wih0[(size_t)r*1024 + c] * iv[tt*HD + c];
  for (int off = 32; off; off >>= 1) s += __shfl_xor(s, off);
  if (lane == 0) base[o] = bih0[r] + s;
}

// X0[b][r] = base[b%2][r] + sum_c W_ih0[r][512+c] * emb[b/2][(b%2)*512+c]
__global__ __launch_bounds__(256) void k_x0(const float* __restrict__ Wih0,
    const float* __restrict__ emb, const float* __restrict__ base, float* __restrict__ X0){
  __shared__ float Wt[64*33];
  __shared__ float Et[64*33];
  int tid = threadIdx.x;
  int r0 = blockIdx.x*64, b0 = blockIdx.y*64;
  int tx = tid & 15, ty = tid >> 4;
  float acc[4][4];
  #pragma unroll
  for (int i=0;i<4;i++)
    #pragma unroll
    for (int j=0;j<4;j++) acc[i][j] = 0.f;
  int lr = tid >> 2, lk = (tid & 3) * 8;
  for (int kk = 0; kk < HD; kk += 32){
    __syncthreads();
    {
      const float4* wg = (const float4*)(Wih0 + (size_t)(r0+lr)*1024 + HD + kk + lk);
      float4 a = wg[0], b = wg[1];
      float* d = Wt + lr*33 + lk;
      d[0]=a.x; d[1]=a.y; d[2]=a.z; d[3]=a.w; d[4]=b.x; d[5]=b.y; d[6]=b.z; d[7]=b.w;
    }
    {
      int bb = b0 + lr; int te = bb >> 1, hf = bb & 1;
      const float4* eg = (const float4*)(emb + (size_t)te*1024 + hf*HD + kk + lk);
      float4 a = eg[0], b = eg[1];
      float* d = Et + lr*33 + lk;
      d[0]=a.x; d[1]=a.y; d[2]=a.z; d[3]=a.w; d[4]=b.x; d[5]=b.y; d[6]=b.z; d[7]=b.w;
    }
    __syncthreads();
    #pragma unroll
    for (int k=0;k<32;k++){
      float wv[4], ev[4];
      #pragma unroll
      for (int i=0;i<4;i++) wv[i] = Wt[(tx*4+i)*33 + k];
      #pragma unroll
      for (int j=0;j<4;j++) ev[j] = Et[(ty*4+j)*33 + k];
      #pragma unroll
      for (int i=0;i<4;i++)
        #pragma unroll
        for (int j=0;j<4;j++) acc[i][j] += wv[i]*ev[j];
    }
  }
  #pragma unroll
  for (int j=0;j<4;j++){
    int bb = b0 + ty*4 + j;
    #pragma unroll
    for (int i=0;i<4;i++){
      int r = r0 + tx*4 + i;
      X0[(size_t)bb*1536 + r] = acc[i][j] + base[(bb&1)*1536 + r];
    }
  }
}

__device__ __forceinline__ void wait_flags(unsigned int* base, int n, unsigned int target, int tid){
  if (tid < 64){
    long iter = 0;
    for (;;){
      unsigned int v = 0;
      if (tid < n)
        v = __hip_atomic_load(base + tid*32, __ATOMIC_ACQUIRE, __HIP_MEMORY_SCOPE_AGENT);
      bool ok = (tid >= n) || (v >= target);
      if (__all((int)ok)) break;
      __builtin_amdgcn_s_sleep(1);
      if (++iter > 2000000L) break;   // safety valve: never hang the bench
    }
  }
  __syncthreads();
}

// Persistent GRU chain. WGs 0..31: layer 0 (16 units/WG). WGs 32..95: layer 1 (8 units/WG).
// Per cell: GEMV (weights in VGPRs, 4 lanes/row) -> LDS reduce -> gates -> ONE group barrier.
// Layer1 consumes outs0 via layer0's flags (pipelined; layer0 never waits).
__global__ __launch_bounds__(256, 1) void k_chain(
    const float* __restrict__ Whh0, const float* __restrict__ Wih1, const float* __restrict__ Whh1,
    const float* __restrict__ bhh0, const float* __restrict__ bih1, const float* __restrict__ bhh1,
    const float* __restrict__ X0, float* __restrict__ outs0, float* __restrict__ o,
    float* h0, float* h1, unsigned int* flags)
{
  const int w = blockIdx.x, tid = threadIdx.x;
  const bool isA = (w < 32);
  __shared__ float red[64];
  float wreg[128];
  const int sub = tid & 3;
  int slot; bool act;
  const float* wsrc = nullptr;
  if (isA){
    int ul = tid >> 4;            // 0..15
    int q  = (tid >> 2) & 3;      // 0..3 (3 = idle)
    int u  = w*16 + ul;
    slot = q; act = (q < 3);
    if (act) wsrc = Whh0 + ((size_t)(q*HD + u)*HD + sub*128);
  } else {
    int wp = w - 32;
    int ul = tid >> 5;            // 0..7
    int s8 = (tid >> 2) & 7;      // 0..7 (6,7 idle)
    int u  = wp*8 + ul;
    slot = s8; act = (s8 < 6);
    if (s8 < 3)      wsrc = Wih1 + ((size_t)(s8*HD + u)*HD + sub*128);
    else if (s8 < 6) wsrc = Whh1 + ((size_t)((s8-3)*HD + u)*HD + sub*128);
  }
  if (wsrc){
    #pragma unroll
    for (int i=0;i<128;i++) wreg[i] = wsrc[i];
  } else {
    #pragma unroll
    for (int i=0;i<128;i++) wreg[i] = 0.f;
  }
  const int nGate = isA ? 16 : 8;
  float gb0=0,gb1=0,gb2=0,gb3=0,gb4=0,gb5=0;
  if (tid < nGate){
    int ug = isA ? (w*16 + tid) : ((w-32)*8 + tid);
    if (isA){ gb0=bhh0[ug]; gb1=bhh0[HD+ug]; gb2=bhh0[2*HD+ug]; }
    else {    gb0=bih1[ug]; gb1=bih1[HD+ug]; gb2=bih1[2*HD+ug];
              gb3=bhh1[ug]; gb4=bhh1[HD+ug]; gb5=bhh1[2*HD+ug]; }
  }
  unsigned int* flagsA = flags;
  unsigned int* flagsB = flags + 32*32;

  for (int c = 0; c < 256; c++){
    if (!isA) wait_flags(flagsA, 32, (unsigned)(c+1), tid);   // outs0[c] ready
    float partial = 0.f;
    if (act){
      const float* xp;
      if (isA) xp = h0 + (c&1)*HD + sub*128;
      else xp = (slot < 3) ? (outs0 + c*HD + sub*128) : (h1 + (c&1)*HD + sub*128);
      const float4* x4 = (const float4*)xp;
      #pragma unroll
      for (int i=0;i<32;i++){
        float4 xv = x4[i];
        partial += wreg[4*i]*xv.x + wreg[4*i+1]*xv.y + wreg[4*i+2]*xv.z + wreg[4*i+3]*xv.w;
      }
    }
    partial += __shfl_xor(partial, 1);
    partial += __shfl_xor(partial, 2);
    if (act && sub == 0){
      if (isA) red[(tid>>4)*4 + slot] = partial;
      else     red[(tid>>5)*8 + slot] = partial;
    }
    __syncthreads();
    if (tid < nGate){
      int ug = isA ? (w*16 + tid) : ((w-32)*8 + tid);
      float ir, iz, in_, hr, hz, hn;
      if (isA){
        const float* xo = X0 + (size_t)c*1536;
        ir = xo[ug]; iz = xo[HD+ug]; in_ = xo[2*HD+ug];
        hr = red[tid*4+0] + gb0; hz = red[tid*4+1] + gb1; hn = red[tid*4+2] + gb2;
      } else {
        ir = red[tid*8+0] + gb0; iz = red[tid*8+1] + gb1; in_ = red[tid*8+2] + gb2;
        hr = red[tid*8+3] + gb3; hz = red[tid*8+4] + gb4; hn = red[tid*8+5] + gb5;
      }
      float* hb = isA ? h0 : h1;
      float hprev = hb[(c&1)*HD + ug];
      float r = 1.f/(1.f + expf(-(ir+hr)));
      float z = 1.f/(1.f + expf(-(iz+hz)));
      float n = tanhf(in_ + r*hn);
      float hnew = (1.f - z)*n + z*hprev;
      hb[((c+1)&1)*HD + ug] = hnew;
      if (isA) outs0[c*HD + ug] = hnew;
      else if ((c & 1) == 0) o[(c>>1)*HD + ug] = hnew;
    }
    __syncthreads();
    if (tid == 0){
      unsigned int* myflag = isA ? (flagsA + w*32) : (flagsB + (w-32)*32);
      __hip_atomic_store(myflag, (unsigned)(c+1), __ATOMIC_RELEASE, __HIP_MEMORY_SCOPE_AGENT);
    }
    if (isA) wait_flags(flagsA, 32, (unsigned)(c+1), tid);
    else     wait_flags(flagsB, 64, (unsigned)(c+1), tid);
  }
}

// logits = o @ out_W.T + out_b -> d_out; per-(t,block) packed (max,~idx) candidates.
__global__ __launch_bounds__(256) void k_logits(const float* __restrict__ o,
    const float* __restrict__ outW, const float* __restrict__ outB,
    float* __restrict__ dout, unsigned long long* __restrict__ pm_part){
  __shared__ float os[128*66];
  __shared__ float wsld[64*66];
  int tid = threadIdx.x;
  int v0 = blockIdx.x * 64;
  float acc[8][4];
  #pragma unroll
  for (int i=0;i<8;i++)
    #pragma unroll
    for (int j=0;j<4;j++) acc[i][j] = 0.f;
  int tx = tid & 15, ty = tid >> 4;
  for (int kk = 0; kk < HD; kk += 64){
    __syncthreads();
    {
      int tloc = tid >> 1, k0 = (tid & 1) * 32;
      const float4* og = (const float4*)(o + (size_t)tloc*HD + kk + k0);
      #pragma unroll
      for (int q=0;q<8;q++){
        float4 x = og[q]; int kb = k0 + q*4;
        os[tloc*66+kb]=x.x; os[tloc*66+kb+1]=x.y; os[tloc*66+kb+2]=x.z; os[tloc*66+kb+3]=x.w;
      }
    }
    {
      int vloc = tid >> 2, k0 = (tid & 3) * 16;
      int v = v0 + vloc;
      if (v < VD){
        const float4* wg = (const float4*)(outW + (size_t)v*HD + kk + k0);
        #pragma unroll
        for (int q=0;q<4;q++){
          float4 x = wg[q]; int kb = k0 + q*4;
          wsld[vloc*66+kb]=x.x; wsld[vloc*66+kb+1]=x.y; wsld[vloc*66+kb+2]=x.z; wsld[vloc*66+kb+3]=x.w;
        }
      } else {
        #pragma unroll
        for (int q=0;q<16;q++) wsld[vloc*66+k0+q] = 0.f;
      }
    }
    __syncthreads();
    #pragma unroll 8
    for (int k=0;k<64;k++){
      float ov[8], wv[4];
      #pragma unroll
      for (int i=0;i<8;i++) ov[i] = os[(tx*8+i)*66 + k];
      #pragma unroll
      for (int j=0;j<4;j++) wv[j] = wsld[(ty*4+j)*66 + k];
      #pragma unroll
      for (int i=0;i<8;i++)
        #pragma unroll
        for (int j=0;j<4;j++) acc[i][j] += ov[i]*wv[j];
    }
  }
  __syncthreads();
  unsigned long long* cand = (unsigned long long*)wsld;  // 128*16*8B = 16KB <= 16.9KB
  float bias[4]; int vj[4];
  #pragma unroll
  for (int j=0;j<4;j++){
    vj[j] = v0 + ty*4 + j;
    bias[j] = (vj[j] < VD) ? outB[vj[j]] : 0.f;
  }
  #pragma unroll
  for (int i=0;i<8;i++){
    int t = tx*8 + i;
    unsigned long long best = 0ull;
    #pragma unroll
    for (int j=0;j<4;j++){
      if (vj[j] < VD){
        float lg = acc[i][j] + bias[j];
        dout[(size_t)t*VD + vj[j]] = lg;
        unsigned b = __float_as_uint(lg);
        unsigned key = (b & 0x80000000u) ? ~b : (b | 0x80000000u);
        unsigned long long p = ((unsigned long long)key << 32) | (unsigned long long)(~(unsigned)vj[j]);
        if (p > best) best = p;
      }
    }
    cand[t*16 + ty] = best;
  }
  __syncthreads();
  if (tid < 128){
    unsigned long long best = 0ull;
    #pragma unroll
    for (int y=0;y<16;y++){
      unsigned long long p = cand[tid*16 + y];
      if (p > best) best = p;
    }
    pm_part[(size_t)tid*NB6 + blockIdx.x] = best;
  }
}

__global__ void k_pmred(const unsigned long long* __restrict__ pm_part,
                        unsigned long long* __restrict__ pm){
  int t = blockIdx.x, tid = threadIdx.x;
  __shared__ unsigned long long s[256];
  unsigned long long best = 0ull;
  for (int i = tid; i < NB6; i += 256){
    unsigned long long p = pm_part[(size_t)t*NB6 + i];
    if (p > best) best = p;
  }
  s[tid] = best; __syncthreads();
  for (int st = 128; st; st >>= 1){
    if (tid < st){ if (s[tid+st] > s[tid]) s[tid] = s[tid+st]; }
    __syncthreads();
  }
  if (tid == 0) pm[t] = s[0];
}

__global__ void k_expsum(float* __restrict__ dout, const unsigned long long* __restrict__ pm,
                         float* __restrict__ sums_part){
  int ch = blockIdx.x, t = blockIdx.y, tid = threadIdx.x;
  unsigned key = (unsigned)(pm[t] >> 32);
  unsigned b = (key & 0x80000000u) ? (key ^ 0x80000000u) : ~key;
  float mx = __uint_as_float(b);
  float s = 0.f;
  for (int q=0;q<8;q++){
    int v = ch*2048 + q*256 + tid;
    if (v < VD){
      float l = dout[(size_t)t*VD + v];
      float p = expf(l - mx);
      dout[(size_t)t*VD + v] = p;
      s += p;
    }
  }
  __shared__ float ss[256];
  ss[tid] = s; __syncthreads();
  for (int st = 128; st; st >>= 1){
    if (tid < st) ss[tid] += ss[tid+st];
    __syncthreads();
  }
  if (tid == 0) sums_part[t*25 + ch] = ss[0];
}

__global__ void k_fin(float* __restrict__ dout, const unsigned long long* __restrict__ pm,
                      const float* __restrict__ sums_part){
  int t = blockIdx.x, tid = threadIdx.x;
  __shared__ float invs;
  if (tid == 0){
    float s = 0.f;
    for (int i=0;i<25;i++) s += sums_part[t*25 + i];
    invs = 1.f / s;
  }
  __syncthreads();
  float iv2 = invs;
  for (int v = tid; v < VD; v += 256) dout[(size_t)t*VD + v] *= iv2;
  if (tid == 0){
    unsigned low = (unsigned)(pm[t] & 0xffffffffu);
    dout[(size_t)TD*VD + t] = (float)(~low);
  }
}

extern "C" void kernel_launch(void* const* d_in, const int* in_sizes, int n_in,
                              void* d_out, int out_size, void* d_ws, size_t ws_size,
                              hipStream_t stream){
  const float* iv   = (const float*)d_in[0];
  const float* tgt  = (const float*)d_in[1];
  const float* sos  = (const float*)d_in[2];
  const float* embW = (const float*)d_in[3];
  const float* embB = (const float*)d_in[4];
  const float* Wih0 = (const float*)d_in[5];
  const float* Whh0 = (const float*)d_in[6];
  const float* bih0 = (const float*)d_in[7];
  const float* bhh0 = (const float*)d_in[8];
  const float* Wih1 = (const float*)d_in[9];
  const float* Whh1 = (const float*)d_in[10];
  const float* bih1 = (const float*)d_in[11];
  const float* bhh1 = (const float*)d_in[12];
  const float* outW = (const float*)d_in[13];
  const float* outB = (const float*)d_in[14];
  (void)in_sizes; (void)n_in; (void)out_size; (void)ws_size;

  float* ws   = (float*)d_ws;
  float* dout = (float*)d_out;
  float* emb   = ws + OFF_EMB;
  float* X0    = ws + OFF_X0;
  float* outs0 = ws + OFF_OUTS0;
  float* o     = ws + OFF_O;
  float* base  = ws + OFF_BASE;
  int*   idx   = (int*)(ws + OFF_IDX);
  float* h0    = ws + OFF_H0;
  float* h1    = ws + OFF_H1;
  unsigned int* flags = (unsigned int*)(ws + OFF_FLAGS);
  unsigned long long* pm      = (unsigned long long*)(ws + OFF_PM);
  unsigned long long* pm_part = (unsigned long long*)(ws + OFF_PMPART);
  float* sums_part = ws + OFF_SUMS;

  // zero h0,h1,flags,pm (contiguous 5376 floats; ws is re-poisoned to 0xAA each call)
  k_zero<<<dim3(21), 256, 0, stream>>>(ws + OFF_H0, 5376);
  k_idx<<<dim3(TD), 256, 0, stream>>>(tgt, sos, idx);
  k_emb<<<dim3(TD,4), 256, 0, stream>>>(embW, embB, idx, emb);
  k_base<<<dim3(768), 256, 0, stream>>>(Wih0, bih0, iv, base);
  k_x0<<<dim3(24,4), 256, 0, stream>>>(Wih0, emb, base, X0);
  k_chain<<<dim3(96), 256, 0, stream>>>(Whh0, Wih1, Whh1, bhh0, bih1, bhh1,
                                        X0, outs0, o, h0, h1, flags);
  k_logits<<<dim3(NB6), 256, 0, stream>>>(o, outW, outB, dout, pm_part);
  k_pmred<<<dim3(TD), 256, 0, stream>>>(pm_part, pm);
  k_expsum<<<dim3(25,TD), 256, 0, stream>>>(dout, pm, sums_part);
  k_fin<<<dim3(TD), 256, 0, stream>>>(dout, pm, sums_part);
}

// Round 2
// 2351.623 us; speedup vs baseline: 1.0487x; 1.0487x over previous
//
#include <hip/hip_runtime.h>
#include <math.h>

#define HD 512
#define VD 50257
#define TD 128
#define NB6 786   // ceil(50257/64)

// ---- ws layout (float offsets) ----
#define OFF_H0     0u        // [257][512]  layer0 h after cell c at row c+1 (row 0 = zeros)
#define OFF_H1     131584u   // [257][512]  layer1 h; o[t] == H1 row 2t+1
#define OFF_X0     263168u   // [256][1536] gi for layer0 (incl. b_ih0)
#define OFF_EMB    656384u   // [128][1024]
#define OFF_BASE   787456u   // [2][1536]
#define OFF_IDX    790528u   // [128] int
#define OFF_FLAGS  790656u   // 64 slots x 32 uints (128B spacing): 0..7 flagsA, 8..23 flagsB,
                             // 32..55 xcc publish, 60 canary flag, 61 canary word
#define OFF_PM     792704u   // [128] ull packed (max,~idx)

#define MAGICW 0x5A17C0DEu

__global__ void k_zero4(float* ws){
  int idx = blockIdx.x*256 + threadIdx.x;
  if (idx < 512) ws[OFF_H0 + idx] = 0.f;
  else if (idx < 1024) ws[OFF_H1 + (idx-512)] = 0.f;
  else if (idx < 3072) ws[OFF_FLAGS + (idx-1024)] = 0.f;
  else if (idx < 3328) ws[OFF_PM + (idx-3072)] = 0.f;
}

__global__ void k_idx(const float* __restrict__ tgt, const float* __restrict__ sos,
                      int* __restrict__ idx){
  int t = blockIdx.x;
  const float* src = (t == 0) ? sos : (tgt + (size_t)(t-1)*VD);
  for (int v = threadIdx.x; v < VD; v += 256)
    if (src[v] > 0.5f) idx[t] = v;   // one-hot: exactly one writer
}

__global__ void k_emb(const float* __restrict__ embW, const float* __restrict__ embB,
                      const int* __restrict__ idx, float* __restrict__ emb){
  int t = blockIdx.x;
  int j = blockIdx.y*256 + threadIdx.x;    // 0..1023
  float v = embW[(size_t)j*VD + idx[t]] + embB[j];
  emb[t*1024 + j] = v > 0.f ? v : 0.f;
}

// base[tt][r] = b_ih0[r] + sum_c W_ih0[r][c] * iv[tt][c]   (c < 512)
__global__ void k_base(const float* __restrict__ Wih0, const float* __restrict__ bih0,
                       const float* __restrict__ iv, float* __restrict__ base){
  int wave = threadIdx.x >> 6, lane = threadIdx.x & 63;
  int o = blockIdx.x*4 + wave;            // 0..3071
  int tt = o / 1536, r = o % 1536;
  float s = 0.f;
  for (int c = lane; c < HD; c += 64)
    s += Wih0[(size_t)r*1024 + c] * iv[tt*HD + c];
  for (int off = 32; off; off >>= 1) s += __shfl_xor(s, off);
  if (lane == 0) base[o] = bih0[r] + s;
}

// X0[b][r] = base[b%2][r] + sum_c W_ih0[r][512+c] * emb[b/2][(b%2)*512+c]
__global__ __launch_bounds__(256) void k_x0(const float* __restrict__ Wih0,
    const float* __restrict__ emb, const float* __restrict__ base, float* __restrict__ X0){
  __shared__ float Wt[64*33];
  __shared__ float Et[64*33];
  int tid = threadIdx.x;
  int r0 = blockIdx.x*64, b0 = blockIdx.y*64;
  int tx = tid & 15, ty = tid >> 4;
  float acc[4][4];
  #pragma unroll
  for (int i=0;i<4;i++)
    #pragma unroll
    for (int j=0;j<4;j++) acc[i][j] = 0.f;
  int lr = tid >> 2, lk = (tid & 3) * 8;
  for (int kk = 0; kk < HD; kk += 32){
    __syncthreads();
    {
      const float4* wg = (const float4*)(Wih0 + (size_t)(r0+lr)*1024 + HD + kk + lk);
      float4 a = wg[0], b = wg[1];
      float* d = Wt + lr*33 + lk;
      d[0]=a.x; d[1]=a.y; d[2]=a.z; d[3]=a.w; d[4]=b.x; d[5]=b.y; d[6]=b.z; d[7]=b.w;
    }
    {
      int bb = b0 + lr; int te = bb >> 1, hf = bb & 1;
      const float4* eg = (const float4*)(emb + (size_t)te*1024 + hf*HD + kk + lk);
      float4 a = eg[0], b = eg[1];
      float* d = Et + lr*33 + lk;
      d[0]=a.x; d[1]=a.y; d[2]=a.z; d[3]=a.w; d[4]=b.x; d[5]=b.y; d[6]=b.z; d[7]=b.w;
    }
    __syncthreads();
    #pragma unroll
    for (int k=0;k<32;k++){
      float wv[4], ev[4];
      #pragma unroll
      for (int i=0;i<4;i++) wv[i] = Wt[(tx*4+i)*33 + k];
      #pragma unroll
      for (int j=0;j<4;j++) ev[j] = Et[(ty*4+j)*33 + k];
      #pragma unroll
      for (int i=0;i<4;i++)
        #pragma unroll
        for (int j=0;j<4;j++) acc[i][j] += wv[i]*ev[j];
    }
  }
  #pragma unroll
  for (int j=0;j<4;j++){
    int bb = b0 + ty*4 + j;
    #pragma unroll
    for (int i=0;i<4;i++){
      int r = r0 + tx*4 + i;
      X0[(size_t)bb*1536 + r] = acc[i][j] + base[(bb&1)*1536 + r];
    }
  }
}

// Persistent GRU chain, 24 real WGs targeted at one XCD via blockIdx%8==0.
// Layer0: WGs 0..7, 64 units/WG, 4 lanes/unit (128 cols each), 384 weight VGPRs/lane.
// Layer1: WGs 8..23, 32 units/WG, 8 lanes/unit (gi half: Wih1, gh half: Whh1).
// One flag-barrier per cell per domain; layer0 never waits on layer1.
// Fast path (co-located on one XCD): plain data stores + syncthreads (vmcnt drain)
// + relaxed agent flag atomics; all data slots are write-once/read-once (fresh lines).
// Heavy path (any placement): agent acquire/release fences around the same protocol.
__global__ __launch_bounds__(256, 1) void k_chain(
    const float* __restrict__ Whh0, const float* __restrict__ Wih1, const float* __restrict__ Whh1,
    const float* __restrict__ bhh0, const float* __restrict__ bih1, const float* __restrict__ bhh1,
    const float* __restrict__ X0, float* __restrict__ H0, float* __restrict__ H1,
    unsigned int* F)
{
  const int b = blockIdx.x;
  if (b & 7) return;               // keep only one XCD's worth (heuristic, not correctness)
  const int i = b >> 3;
  if (i >= 24) return;
  const int tid = threadIdx.x;
  const bool isA = (i < 8);
  __shared__ int sh_fast;

  // ---- placement detection: XCC id (hwreg 20, offset 0, size 32) + same-L2 canary ----
  unsigned own = 0;
  if (tid < 64) own = ((unsigned)__builtin_amdgcn_s_getreg(63508)) & 0xFFu;
  if (i == 0 && tid == 0){
    F[61*32] = MAGICW;                                  // plain store -> local L2 (dirty)
    asm volatile("s_waitcnt vmcnt(0)" ::: "memory");
    __hip_atomic_store(&F[60*32], 1u, __ATOMIC_RELAXED, __HIP_MEMORY_SCOPE_AGENT);
  }
  if (tid == 0)
    __hip_atomic_store(&F[(32+i)*32], own | 0x100u, __ATOMIC_RELAXED, __HIP_MEMORY_SCOPE_AGENT);
  if (tid < 64){
    bool actp = (tid < 25);
    unsigned tgt = (tid < 24) ? 0x100u : 1u;
    unsigned int* pp = (tid < 24) ? &F[(32+tid)*32] : &F[60*32];
    unsigned v = 0; long it = 0;
    for (;;){
      v = actp ? __hip_atomic_load(pp, __ATOMIC_RELAXED, __HIP_MEMORY_SCOPE_AGENT) : 0xFFFFFFFFu;
      if (__all((int)(!actp || v >= tgt))) break;
      __builtin_amdgcn_s_sleep(8);
      if (++it > 3000000L) break;                       // safety valve
    }
    asm volatile("" ::: "memory");
    bool ok = true;
    if (tid < 24) ok = ((v & 0xFFu) == own);
    else if (tid == 24){ unsigned cv = F[61*32]; ok = (cv == MAGICW); }  // plain (cached) load
    ok = __all((int)ok) != 0;
    if (tid == 0) sh_fast = ok ? 1 : 0;
  }
  __syncthreads();
  const bool fastf = (sh_fast != 0);

  // ---- pin weights in VGPRs ----
  float w0[128], w1[128], w2[128];
  int u, q, qq;
  unsigned myflag;
  if (isA){
    u = i*64 + (tid >> 2); q = tid & 3; qq = q;
    myflag = (unsigned)(i*32);
  } else {
    int p = i - 8;
    u = p*32 + (tid >> 3); q = tid & 7; qq = q & 3;
    myflag = (unsigned)((8+p)*32);
  }
  {
    const float* Wsrc = isA ? Whh0 : ((q < 4) ? Wih1 : Whh1);
    const float4* p0 = (const float4*)(Wsrc + ((size_t)(0*HD + u))*HD + qq*128);
    const float4* p1 = (const float4*)(Wsrc + ((size_t)(1*HD + u))*HD + qq*128);
    const float4* p2 = (const float4*)(Wsrc + ((size_t)(2*HD + u))*HD + qq*128);
    #pragma unroll
    for (int j=0;j<32;j++){
      float4 a = p0[j]; w0[4*j]=a.x; w0[4*j+1]=a.y; w0[4*j+2]=a.z; w0[4*j+3]=a.w;
      float4 bb = p1[j]; w1[4*j]=bb.x; w1[4*j+1]=bb.y; w1[4*j+2]=bb.z; w1[4*j+3]=bb.w;
      float4 cc = p2[j]; w2[4*j]=cc.x; w2[4*j+1]=cc.y; w2[4*j+2]=cc.z; w2[4*j+3]=cc.w;
    }
  }
  const bool writer = isA ? ((tid & 3) == 0) : ((tid & 7) == 0);
  float br=0.f,bz=0.f,bn=0.f, b2r=0.f,b2z=0.f,b2n=0.f, hprev=0.f;
  if (writer){
    if (isA){ br = bhh0[u]; bz = bhh0[HD+u]; bn = bhh0[2*HD+u]; }
    else { br = bih1[u]; bz = bih1[HD+u]; bn = bih1[2*HD+u];
           b2r = bhh1[u]; b2z = bhh1[HD+u]; b2n = bhh1[2*HD+u]; }
  }
  const int nPoll = isA ? 8 : 24;
  const bool act = (tid < nPoll);
  const int addv = (!isA && tid < 8) ? 1 : 0;
  unsigned int* pollp = &F[(tid & 63)*32];

  for (int c = 0; c < 256; c++){
    // prefetch static gi for layer0 writers (independent of the barrier)
    float xr=0.f, xz=0.f, xn=0.f;
    if (isA && writer){
      const float* xo = X0 + (size_t)c*1536 + u;
      xr = xo[0]; xz = xo[HD]; xn = xo[2*HD];
    }
    // wait: layer0 -> own 8 flags >= c ; layer1 -> A flags >= c+1 and B flags >= c
    if (tid < 64){
      long it = 0;
      for (;;){
        int v = act ? (int)__hip_atomic_load(pollp, __ATOMIC_RELAXED, __HIP_MEMORY_SCOPE_AGENT)
                    : 0x7FFFFFFF;
        if (__all((int)(v >= c + addv))) break;
        if (!fastf) __builtin_amdgcn_s_sleep(2);
        if (++it > 3000000L) break;                     // safety valve
      }
      if (!fastf) __builtin_amdgcn_fence(__ATOMIC_ACQUIRE, "agent");
    }
    __syncthreads();
    // GEMV slice: 384 fma into 3 gate accumulators
    const float4* x4;
    if (isA) x4 = (const float4*)(H0 + (size_t)c*HD + q*128);
    else x4 = (q < 4) ? (const float4*)(H0 + (size_t)(c+1)*HD + qq*128)
                      : (const float4*)(H1 + (size_t)c*HD + qq*128);
    float ar=0.f, az=0.f, an=0.f;
    #pragma unroll
    for (int j=0;j<32;j++){
      float4 xv = x4[j];
      ar = fmaf(w0[4*j+0], xv.x, ar); ar = fmaf(w0[4*j+1], xv.y, ar);
      ar = fmaf(w0[4*j+2], xv.z, ar); ar = fmaf(w0[4*j+3], xv.w, ar);
      az = fmaf(w1[4*j+0], xv.x, az); az = fmaf(w1[4*j+1], xv.y, az);
      az = fmaf(w1[4*j+2], xv.z, az); az = fmaf(w1[4*j+3], xv.w, az);
      an = fmaf(w2[4*j+0], xv.x, an); an = fmaf(w2[4*j+1], xv.y, an);
      an = fmaf(w2[4*j+2], xv.z, an); an = fmaf(w2[4*j+3], xv.w, an);
    }
    ar += __shfl_xor(ar, 1); az += __shfl_xor(az, 1); an += __shfl_xor(an, 1);
    ar += __shfl_xor(ar, 2); az += __shfl_xor(az, 2); an += __shfl_xor(an, 2);
    float or_=0.f, oz=0.f, on=0.f;
    if (!isA){ or_ = __shfl_xor(ar, 4); oz = __shfl_xor(az, 4); on = __shfl_xor(an, 4); }
    if (writer){
      float g_ir, g_iz, g_in, g_hr, g_hz, g_hn;
      if (isA){ g_ir = xr; g_iz = xz; g_in = xn;
                g_hr = ar + br; g_hz = az + bz; g_hn = an + bn; }
      else    { g_ir = ar + br;  g_iz = az + bz;  g_in = an + bn;
                g_hr = or_ + b2r; g_hz = oz + b2z; g_hn = on + b2n; }
      float r = 1.f/(1.f + expf(-(g_ir + g_hr)));
      float z = 1.f/(1.f + expf(-(g_iz + g_hz)));
      float n = tanhf(g_in + r*g_hn);
      float hnew = (1.f - z)*n + z*hprev;
      hprev = hnew;
      if (isA) H0[(size_t)(c+1)*HD + u] = hnew;
      else     H1[(size_t)(c+1)*HD + u] = hnew;
    }
    __syncthreads();                                    // drains vmcnt before s_barrier
    if (tid == 0){
      if (!fastf) __builtin_amdgcn_fence(__ATOMIC_RELEASE, "agent");
      __hip_atomic_store(&F[myflag], (unsigned)(c+1), __ATOMIC_RELAXED, __HIP_MEMORY_SCOPE_AGENT);
    }
  }
}

// logits = o @ out_W.T + out_b -> d_out; o[t] = H1 row (2t+1). Fused argmax via atomicMax.
__global__ __launch_bounds__(256) void k_logits(const float* __restrict__ H1,
    const float* __restrict__ outW, const float* __restrict__ outB,
    float* __restrict__ dout, unsigned long long* __restrict__ pm){
  __shared__ float os[128*66];
  __shared__ float wsld[64*66];
  int tid = threadIdx.x;
  int v0 = blockIdx.x * 64;
  float acc[8][4];
  #pragma unroll
  for (int i=0;i<8;i++)
    #pragma unroll
    for (int j=0;j<4;j++) acc[i][j] = 0.f;
  int tx = tid & 15, ty = tid >> 4;
  for (int kk = 0; kk < HD; kk += 64){
    __syncthreads();
    {
      int tloc = tid >> 1, k0 = (tid & 1) * 32;
      const float4* og = (const float4*)(H1 + (size_t)(2*tloc+1)*HD + kk + k0);
      #pragma unroll
      for (int q=0;q<8;q++){
        float4 x = og[q]; int kb = k0 + q*4;
        os[tloc*66+kb]=x.x; os[tloc*66+kb+1]=x.y; os[tloc*66+kb+2]=x.z; os[tloc*66+kb+3]=x.w;
      }
    }
    {
      int vloc = tid >> 2, k0 = (tid & 3) * 16;
      int v = v0 + vloc;
      if (v < VD){
        const float4* wg = (const float4*)(outW + (size_t)v*HD + kk + k0);
        #pragma unroll
        for (int q=0;q<4;q++){
          float4 x = wg[q]; int kb = k0 + q*4;
          wsld[vloc*66+kb]=x.x; wsld[vloc*66+kb+1]=x.y; wsld[vloc*66+kb+2]=x.z; wsld[vloc*66+kb+3]=x.w;
        }
      } else {
        #pragma unroll
        for (int q=0;q<16;q++) wsld[vloc*66+k0+q] = 0.f;
      }
    }
    __syncthreads();
    #pragma unroll 8
    for (int k=0;k<64;k++){
      float ov[8], wv[4];
      #pragma unroll
      for (int i=0;i<8;i++) ov[i] = os[(tx*8+i)*66 + k];
      #pragma unroll
      for (int j=0;j<4;j++) wv[j] = wsld[(ty*4+j)*66 + k];
      #pragma unroll
      for (int i=0;i<8;i++)
        #pragma unroll
        for (int j=0;j<4;j++) acc[i][j] += ov[i]*wv[j];
    }
  }
  __syncthreads();
  unsigned long long* cand = (unsigned long long*)wsld;  // 128*16*8B = 16KB
  float bias[4]; int vj[4];
  #pragma unroll
  for (int j=0;j<4;j++){
    vj[j] = v0 + ty*4 + j;
    bias[j] = (vj[j] < VD) ? outB[vj[j]] : 0.f;
  }
  #pragma unroll
  for (int i=0;i<8;i++){
    int t = tx*8 + i;
    unsigned long long best = 0ull;
    #pragma unroll
    for (int j=0;j<4;j++){
      if (vj[j] < VD){
        float lg = acc[i][j] + bias[j];
        dout[(size_t)t*VD + vj[j]] = lg;
        unsigned bq = __float_as_uint(lg);
        unsigned key = (bq & 0x80000000u) ? ~bq : (bq | 0x80000000u);
        unsigned long long p = ((unsigned long long)key << 32) | (unsigned long long)(~(unsigned)vj[j]);
        if (p > best) best = p;
      }
    }
    cand[t*16 + ty] = best;
  }
  __syncthreads();
  if (tid < 128){
    unsigned long long best = 0ull;
    #pragma unroll
    for (int y=0;y<16;y++){
      unsigned long long p = cand[tid*16 + y];
      if (p > best) best = p;
    }
    atomicMax(pm + tid, best);
  }
}

__global__ void k_expsum(float* __restrict__ dout, const unsigned long long* __restrict__ pm,
                         float* __restrict__ sums_part){
  int ch = blockIdx.x, t = blockIdx.y, tid = threadIdx.x;
  unsigned key = (unsigned)(pm[t] >> 32);
  unsigned b = (key & 0x80000000u) ? (key ^ 0x80000000u) : ~key;
  float mx = __uint_as_float(b);
  float s = 0.f;
  for (int q=0;q<8;q++){
    int v = ch*2048 + q*256 + tid;
    if (v < VD){
      float l = dout[(size_t)t*VD + v];
      float p = expf(l - mx);
      dout[(size_t)t*VD + v] = p;
      s += p;
    }
  }
  __shared__ float ss[256];
  ss[tid] = s; __syncthreads();
  for (int st = 128; st; st >>= 1){
    if (tid < st) ss[tid] += ss[tid+st];
    __syncthreads();
  }
  if (tid == 0) sums_part[t*25 + ch] = ss[0];
}

__global__ void k_fin(float* __restrict__ dout, const unsigned long long* __restrict__ pm,
                      const float* __restrict__ sums_part){
  int t = blockIdx.x, tid = threadIdx.x;
  __shared__ float invs;
  if (tid == 0){
    float s = 0.f;
    for (int i=0;i<25;i++) s += sums_part[t*25 + i];
    invs = 1.f / s;
  }
  __syncthreads();
  float iv2 = invs;
  for (int v = tid; v < VD; v += 256) dout[(size_t)t*VD + v] *= iv2;
  if (tid == 0){
    unsigned low = (unsigned)(pm[t] & 0xffffffffu);
    dout[(size_t)TD*VD + t] = (float)(~low);
  }
}

extern "C" void kernel_launch(void* const* d_in, const int* in_sizes, int n_in,
                              void* d_out, int out_size, void* d_ws, size_t ws_size,
                              hipStream_t stream){
  const float* iv   = (const float*)d_in[0];
  const float* tgt  = (const float*)d_in[1];
  const float* sos  = (const float*)d_in[2];
  const float* embW = (const float*)d_in[3];
  const float* embB = (const float*)d_in[4];
  const float* Wih0 = (const float*)d_in[5];
  const float* Whh0 = (const float*)d_in[6];
  const float* bih0 = (const float*)d_in[7];
  const float* bhh0 = (const float*)d_in[8];
  const float* Wih1 = (const float*)d_in[9];
  const float* Whh1 = (const float*)d_in[10];
  const float* bih1 = (const float*)d_in[11];
  const float* bhh1 = (const float*)d_in[12];
  const float* outW = (const float*)d_in[13];
  const float* outB = (const float*)d_in[14];
  (void)in_sizes; (void)n_in; (void)out_size; (void)ws_size;

  float* ws   = (float*)d_ws;
  float* dout = (float*)d_out;
  float* H0   = ws + OFF_H0;
  float* H1   = ws + OFF_H1;
  float* X0   = ws + OFF_X0;
  float* emb  = ws + OFF_EMB;
  float* base = ws + OFF_BASE;
  int*   idx  = (int*)(ws + OFF_IDX);
  unsigned int* F = (unsigned int*)(ws + OFF_FLAGS);
  unsigned long long* pm = (unsigned long long*)(ws + OFF_PM);
  float* sums_part = ws + OFF_PM + 256;   // [128*25] floats right after pm

  k_zero4<<<dim3(13), 256, 0, stream>>>(ws);
  k_idx<<<dim3(TD), 256, 0, stream>>>(tgt, sos, idx);
  k_emb<<<dim3(TD,4), 256, 0, stream>>>(embW, embB, idx, emb);
  k_base<<<dim3(768), 256, 0, stream>>>(Wih0, bih0, iv, base);
  k_x0<<<dim3(24,4), 256, 0, stream>>>(Wih0, emb, base, X0);
  k_chain<<<dim3(185), 256, 0, stream>>>(Whh0, Wih1, Whh1, bhh0, bih1, bhh1,
                                         X0, H0, H1, F);
  k_logits<<<dim3(NB6), 256, 0, stream>>>(H1, outW, outB, dout, pm);
  k_expsum<<<dim3(25,TD), 256, 0, stream>>>(dout, pm, sums_part);
  k_fin<<<dim3(TD), 256, 0, stream>>>(dout, pm, sums_part);
}